// Round 1
// baseline (986.738 us; speedup 1.0000x reference)
//
#include <hip/hip_runtime.h>
#include <math.h>

#define NFEAT 65536
#define KS1   32        // k-split for K1
#define KC1   2048      // K per block (NFEAT/KS1)
#define KW1   512       // K per wave (KC1/4)

// ws layout (float offsets)
#define WS_ZPART 0                   // [32][1024][64] split-K GEMM partials
#define WS_SCAL  2097152             // [64]: 0=freq_loss 1=roi_loss   (memset 0)
#define WS_SS    2097216             // [1024] sum(flat^2) per batch   (memset 0)
#define WS_FSP   2098240             // [16][32][64] softplus(freq_factors)
#define WS_R1SP  2131008             // [16][32][32]
#define WS_R2SP  2147392             // [16][32][32]
#define WS_G     2163776             // [16][32][32] Gram per group
#define WS_T     2180160             // [1024][32]
#define WS_LOSSB 2212928             // [1024]

__device__ __forceinline__ float softplusf(float x) {
    return fmaxf(x, 0.f) + log1pf(expf(-fabsf(x)));
}

// ---- K0a: softplus all factor tensors into contiguous ws region ----
__global__ __launch_bounds__(256) void k0_factors(const float* __restrict__ ff,
                                                  const float* __restrict__ r1,
                                                  const float* __restrict__ r2,
                                                  float* __restrict__ ws) {
    int i = blockIdx.x * 256 + threadIdx.x;   // 0..65535
    float x;
    if (i < 32768)      x = ff[i];
    else if (i < 49152) x = r1[i - 32768];
    else                x = r2[i - 49152];
    ws[WS_FSP + i] = softplusf(x);
}

// ---- K0b: variance losses (ddof=1 over 16 groups) ----
__global__ __launch_bounds__(256) void k0_varloss(float* __restrict__ ws) {
    int gid = blockIdx.x * 256 + threadIdx.x;  // 12 blocks: 0..3071
    float contrib = 0.f;
    if (gid < 2048) {                 // freq pair p = z*64+f
        const float* F = ws + WS_FSP + gid;
        float sx = 0.f, sx2 = 0.f;
        #pragma unroll
        for (int g = 0; g < 16; g++) { float x = F[g * 2048]; sx += x; sx2 += x * x; }
        contrib = (sx2 - sx * sx * (1.f / 16.f)) * (1.f / 15.f) * (1.f / 64.f);
    } else {                          // roi pair p = z*32+r
        int p = gid - 2048;
        const float* A = ws + WS_R1SP + p;
        const float* B = ws + WS_R2SP + p;
        float sx = 0.f, sx2 = 0.f, tx = 0.f, tx2 = 0.f;
        #pragma unroll
        for (int g = 0; g < 16; g++) {
            float x = A[g * 1024]; sx += x; sx2 += x * x;
            float y = B[g * 1024]; tx += y; tx2 += y * y;
        }
        contrib = ((sx2 - sx * sx * (1.f / 16.f)) + (tx2 - tx * tx * (1.f / 16.f)))
                  * (1.f / 15.f) * (1.f / 32.f);
    }
    __shared__ float red[256];
    red[threadIdx.x] = contrib;
    __syncthreads();
    for (int o = 128; o > 0; o >>= 1) {
        if (threadIdx.x < o) red[threadIdx.x] += red[threadIdx.x + o];
        __syncthreads();
    }
    if (threadIdx.x == 0)
        atomicAdd(ws + WS_SCAL + (blockIdx.x < 8 ? 0 : 1), red[0]);
}

// ---- K0c: per-group Gram  G[z1,z2] = (F.F')(R1.R1')(R2.R2') ----
__global__ __launch_bounds__(256) void k0_gram(float* __restrict__ ws) {
    int g = blockIdx.x, t = threadIdx.x;
    __shared__ float Fg[2048], R1g[1024], R2g[1024];
    for (int i = t; i < 2048; i += 256) Fg[i] = ws[WS_FSP + g * 2048 + i];
    for (int i = t; i < 1024; i += 256) {
        R1g[i] = ws[WS_R1SP + g * 1024 + i];
        R2g[i] = ws[WS_R2SP + g * 1024 + i];
    }
    __syncthreads();
    for (int p = t; p < 1024; p += 256) {
        int z1 = p >> 5, z2 = p & 31;
        float dF = 0.f;
        for (int f = 0; f < 64; f++) dF += Fg[z1 * 64 + f] * Fg[z2 * 64 + f];
        float d1 = 0.f, d2 = 0.f;
        for (int r = 0; r < 32; r++) {
            d1 += R1g[z1 * 32 + r] * R1g[z2 * 32 + r];
            d2 += R2g[z1 * 32 + r] * R2g[z2 * 32 + r];
        }
        ws[WS_G + g * 1024 + p] = dF * d1 * d2;
    }
}

// ---- K1: encoder GEMM (split-K partials) + fused sum(flat^2) ----
// wave = 64 rows x 64 cols (32 of W1, 32 of W2); acc in VGPRs, W via uniform ptr
__global__ __launch_bounds__(256) void k1_gemm(const float* __restrict__ feat,
                                               const float* __restrict__ W1,
                                               const float* __restrict__ W2,
                                               float* __restrict__ ws) {
    __shared__ float red[4][4096];   // 64 KB: per-wave acc for cross-wave reduce
    const int tid  = threadIdx.x;
    const int w    = __builtin_amdgcn_readfirstlane(tid >> 6);  // force wave-uniform
    const int lane = tid & 63;
    const int rt   = blockIdx.x;     // 0..15 row tile
    const int ks   = blockIdx.y;     // 0..31 k slice
    const int row  = rt * 64 + lane;
    const int kbase = ks * KC1 + w * KW1;
    const float* fp  = feat + (size_t)row * NFEAT + kbase;
    const float* w1p = W1 + (size_t)kbase * 32;
    const float* w2p = W2 + (size_t)kbase * 32;

    float acc[64];
    #pragma unroll
    for (int c = 0; c < 64; c++) acc[c] = 0.f;
    float ssl = 0.f;

    for (int k32 = 0; k32 < KW1; k32 += 32) {
        float4 a[8];
        #pragma unroll
        for (int q = 0; q < 8; q++) a[q] = *(const float4*)(fp + k32 + q * 4);
        #pragma unroll
        for (int q = 0; q < 8; q++) {
            #pragma unroll
            for (int j = 0; j < 4; j++) {
                float av = (j == 0) ? a[q].x : (j == 1) ? a[q].y : (j == 2) ? a[q].z : a[q].w;
                ssl = fmaf(av, av, ssl);
                const float* r1 = w1p + (size_t)(k32 + q * 4 + j) * 32;
                const float* r2 = w2p + (size_t)(k32 + q * 4 + j) * 32;
                #pragma unroll
                for (int c = 0; c < 32; c++) acc[c]      = fmaf(av, r1[c], acc[c]);
                #pragma unroll
                for (int c = 0; c < 32; c++) acc[32 + c] = fmaf(av, r2[c], acc[32 + c]);
            }
        }
    }
    atomicAdd(ws + WS_SS + row, ssl);

    #pragma unroll
    for (int q = 0; q < 16; q++) {
        float4 v = make_float4(acc[q * 4], acc[q * 4 + 1], acc[q * 4 + 2], acc[q * 4 + 3]);
        *(float4*)&red[w][lane * 64 + q * 4] = v;
    }
    __syncthreads();
    float* zp = ws + WS_ZPART + ((size_t)ks * 1024 + rt * 64) * 64;
    #pragma unroll
    for (int q = 0; q < 4; q++) {
        int cell = q * 1024 + tid * 4;
        float4 s0 = *(const float4*)&red[0][cell];
        float4 s1 = *(const float4*)&red[1][cell];
        float4 s2 = *(const float4*)&red[2][cell];
        float4 s3 = *(const float4*)&red[3][cell];
        float4 o = make_float4(s0.x + s1.x + s2.x + s3.x, s0.y + s1.y + s2.y + s3.y,
                               s0.z + s1.z + s2.z + s3.z, s0.w + s1.w + s2.w + s3.w);
        *(float4*)&zp[cell] = o;
    }
}

// ---- K2: T[b,z] = sum_{f,r,s} flat*F[z,f]*R1[z,r]*R2[z,s]  (block per batch) ----
__global__ __launch_bounds__(256) void k2_T(const float* __restrict__ feat,
                                            const int* __restrict__ groups,
                                            float* __restrict__ ws) {
    const int b = blockIdx.x;
    const int tid = threadIdx.x;
    const int z  = tid & 31;
    const int rg = tid >> 5;         // 0..7 -> rows rg*4..rg*4+3
    const int g = groups[b];

    float4 r2q[8];
    const float* R2g = ws + WS_R2SP + g * 1024 + z * 32;
    #pragma unroll
    for (int q = 0; q < 8; q++) r2q[q] = *(const float4*)(R2g + q * 4);
    float r1v[4];
    const float* R1g = ws + WS_R1SP + g * 1024 + z * 32 + rg * 4;
    #pragma unroll
    for (int i = 0; i < 4; i++) r1v[i] = R1g[i];
    const float* Fzp = ws + WS_FSP + g * 2048 + z * 64;
    const float* fb = feat + (size_t)b * NFEAT;

    float tacc = 0.f;
    for (int f = 0; f < 64; f++) {
        float facc = 0.f;
        #pragma unroll
        for (int i = 0; i < 4; i++) {
            const float4* rowp = (const float4*)(fb + f * 1024 + (rg * 4 + i) * 32);
            float d = 0.f;
            #pragma unroll
            for (int q = 0; q < 8; q++) {
                float4 v = rowp[q];
                d += v.x * r2q[q].x + v.y * r2q[q].y + v.z * r2q[q].z + v.w * r2q[q].w;
            }
            facc = fmaf(r1v[i], d, facc);
        }
        tacc = fmaf(Fzp[f], facc, tacc);
    }
    __shared__ float sT[8][32];
    sT[rg][z] = tacc;
    __syncthreads();
    if (tid < 32) {
        float s = 0.f;
        #pragma unroll
        for (int r = 0; r < 8; r++) s += sT[r][tid];
        ws[WS_T + b * 32 + tid] = s;
    }
}

// ---- K3: per-batch epilogue (block=64 threads per batch) ----
__global__ __launch_bounds__(64) void k3_batch(const float* __restrict__ W1,
                                               const float* __restrict__ W2,
                                               const float* __restrict__ b1,
                                               const float* __restrict__ b2,
                                               const float* __restrict__ gemb,
                                               const float* __restrict__ noise,
                                               const float* __restrict__ linW,
                                               const float* __restrict__ linb,
                                               const float* __restrict__ lbias,
                                               const int* __restrict__ groups,
                                               const int* __restrict__ labels,
                                               const float* __restrict__ weights,
                                               float* __restrict__ ws) {
    const int b = blockIdx.x;
    const int t = threadIdx.x;   // 0..63
    const int g = groups[b];
    // reduce split-K partials: col t
    float sum = 0.f;
    const float* zp = ws + WS_ZPART + (size_t)b * 64 + t;
    for (int ks = 0; ks < KS1; ks++) sum += zp[(size_t)ks * 65536];

    __shared__ float s_mu[32], s_sig[32], s_zs0[32], s_zs[32], s_P[32], s_red[96];
    float ge0 = gemb[g * 2], ge1 = gemb[g * 2 + 1];
    if (t < 32) {
        float mu = sum + ge0 * W1[(size_t)65536 * 32 + t] + ge1 * W1[(size_t)65537 * 32 + t] + b1[t];
        s_mu[t] = mu;
    } else {
        int c = t - 32;
        float ls = sum + ge0 * W2[(size_t)65536 * 32 + c] + ge1 * W2[(size_t)65537 * 32 + c] + b2[c];
        s_sig[c] = 1e-6f + expf(ls);
    }
    __syncthreads();
    if (t < 32) s_zs0[t] = s_mu[t] + s_sig[t] * noise[b * 32 + t];
    __syncthreads();
    if (t < 32) {
        float d = linb[t];
        for (int i = 0; i < 32; i++) d = fmaf(s_zs0[i], linW[i * 32 + t], d);
        s_zs[t] = d;
        s_P[t] = softplusf(d);
    }
    __syncthreads();
    if (t < 32) {
        float mu = s_mu[t], sg = s_sig[t];
        float kld = -logf(sg) + 0.5f * (sg * sg + mu * mu - 1.f);
        float pt = s_P[t] * ws[WS_T + b * 32 + t];
        const float* Grow = ws + WS_G + g * 1024 + t * 32;
        float gd = 0.f;
        for (int j = 0; j < 32; j++) gd = fmaf(Grow[j], s_P[j], gd);
        s_red[t] = kld; s_red[32 + t] = pt; s_red[64 + t] = s_P[t] * gd;
    }
    __syncthreads();
    if (t == 0) {
        float kld = 0.f, pt = 0.f, pgp = 0.f;
        for (int i = 0; i < 32; i++) { kld += s_red[i]; pt += s_red[32 + i]; pgp += s_red[64 + i]; }
        float rec = (ws[WS_SS + b] - 2.f * pt + pgp) * (1.f / 65536.f);
        float l0 = s_zs[0] + lbias[0], l1 = s_zs[1] + lbias[1];
        float l2 = s_zs[2] + lbias[2], l3 = 1.f + lbias[3];
        float m = fmaxf(fmaxf(l0, l1), fmaxf(l2, l3));
        float lse = m + logf(expf(l0 - m) + expf(l1 - m) + expf(l2 - m) + expf(l3 - m));
        int lb = labels[b];
        float ll = ((lb == 0) ? l0 : (lb == 1) ? l1 : (lb == 2) ? l2 : l3) - lse;
        ws[WS_LOSSB + b] = rec - weights[b] * ll + kld;
    }
}

// ---- K4: final scalar ----
__global__ __launch_bounds__(256) void k4_final(const float* __restrict__ ws, float* __restrict__ out) {
    __shared__ float red[256];
    int t = threadIdx.x;
    float s = 0.f;
    for (int i = t; i < 1024; i += 256) s += ws[WS_LOSSB + i];
    red[t] = s;
    __syncthreads();
    for (int o = 128; o > 0; o >>= 1) {
        if (t < o) red[t] += red[t + o];
        __syncthreads();
    }
    if (t == 0) out[0] = red[0] * (1.f / 1024.f) + ws[WS_SCAL] + ws[WS_SCAL + 1];
}

extern "C" void kernel_launch(void* const* d_in, const int* in_sizes, int n_in,
                              void* d_out, int out_size, void* d_ws, size_t ws_size,
                              hipStream_t stream) {
    const float* feat    = (const float*)d_in[0];
    const int*   labels  = (const int*)d_in[1];
    const int*   groups  = (const int*)d_in[2];
    const float* weights = (const float*)d_in[3];
    const float* noise   = (const float*)d_in[4];
    const float* gemb    = (const float*)d_in[5];
    const float* W1      = (const float*)d_in[6];
    const float* b1      = (const float*)d_in[7];
    const float* W2      = (const float*)d_in[8];
    const float* b2      = (const float*)d_in[9];
    const float* ff      = (const float*)d_in[10];
    const float* r1f     = (const float*)d_in[11];
    const float* r2f     = (const float*)d_in[12];
    const float* linW    = (const float*)d_in[13];
    const float* linb    = (const float*)d_in[14];
    const float* lbias   = (const float*)d_in[15];
    float* ws = (float*)d_ws;
    float* out = (float*)d_out;

    // zero only the atomically-accumulated regions (SCAL + SS)
    hipMemsetAsync(ws + WS_SCAL, 0, (64 + 1024) * sizeof(float), stream);

    k0_factors<<<256, 256, 0, stream>>>(ff, r1f, r2f, ws);
    k0_varloss<<<12, 256, 0, stream>>>(ws);
    k0_gram<<<16, 256, 0, stream>>>(ws);
    k1_gemm<<<dim3(16, KS1), 256, 0, stream>>>(feat, W1, W2, ws);
    k2_T<<<1024, 256, 0, stream>>>(feat, groups, ws);
    k3_batch<<<1024, 64, 0, stream>>>(W1, W2, b1, b2, gemb, noise, linW, linb, lbias,
                                      groups, labels, weights, ws);
    k4_final<<<1, 256, 0, stream>>>(ws, out);
}

// Round 2
// 580.311 us; speedup vs baseline: 1.7004x; 1.7004x over previous
//
#include <hip/hip_runtime.h>
#include <math.h>

#define NFEAT 65536
#define KS1   32        // k-split for K1 (chunk 2048)

// ws layout (float offsets)
#define WS_ZPART 0                   // [32][1024][64] split-K GEMM partials
#define WS_SCAL  2097152             // [64]: 0=freq_loss 1=roi_loss   (memset 0)
#define WS_FSP   2097216             // [16][32][64] softplus(freq_factors)
#define WS_R1SP  2129984             // [16][32][32]
#define WS_R2SP  2146368             // [16][32][32]
#define WS_G     2162752             // [16][32][32] Gram per group
#define WS_TP    2179136             // [8][1024][32] T partials per f-slice
#define WS_SSP   2441280             // [8][1024] sum(flat^2) partials
#define WS_LOSSB 2449472             // [1024]

typedef __bf16 bf16x8 __attribute__((ext_vector_type(8)));
typedef float  floatx4 __attribute__((ext_vector_type(4)));

__device__ __forceinline__ float softplusf(float x) {
    return fmaxf(x, 0.f) + log1pf(expf(-fabsf(x)));
}

// ---- K0a: softplus all factor tensors into contiguous ws region ----
__global__ __launch_bounds__(256) void k0_factors(const float* __restrict__ ff,
                                                  const float* __restrict__ r1,
                                                  const float* __restrict__ r2,
                                                  float* __restrict__ ws) {
    int i = blockIdx.x * 256 + threadIdx.x;   // 0..65535
    float x;
    if (i < 32768)      x = ff[i];
    else if (i < 49152) x = r1[i - 32768];
    else                x = r2[i - 49152];
    ws[WS_FSP + i] = softplusf(x);
}

// ---- K0b: variance losses (ddof=1 over 16 groups) ----
__global__ __launch_bounds__(256) void k0_varloss(float* __restrict__ ws) {
    int gid = blockIdx.x * 256 + threadIdx.x;  // 12 blocks: 0..3071
    float contrib = 0.f;
    if (gid < 2048) {                 // freq pair p = z*64+f
        const float* F = ws + WS_FSP + gid;
        float sx = 0.f, sx2 = 0.f;
        #pragma unroll
        for (int g = 0; g < 16; g++) { float x = F[g * 2048]; sx += x; sx2 += x * x; }
        contrib = (sx2 - sx * sx * (1.f / 16.f)) * (1.f / 15.f) * (1.f / 64.f);
    } else {                          // roi pair p = z*32+r
        int p = gid - 2048;
        const float* A = ws + WS_R1SP + p;
        const float* B = ws + WS_R2SP + p;
        float sx = 0.f, sx2 = 0.f, tx = 0.f, tx2 = 0.f;
        #pragma unroll
        for (int g = 0; g < 16; g++) {
            float x = A[g * 1024]; sx += x; sx2 += x * x;
            float y = B[g * 1024]; tx += y; tx2 += y * y;
        }
        contrib = ((sx2 - sx * sx * (1.f / 16.f)) + (tx2 - tx * tx * (1.f / 16.f)))
                  * (1.f / 15.f) * (1.f / 32.f);
    }
    __shared__ float red[256];
    red[threadIdx.x] = contrib;
    __syncthreads();
    for (int o = 128; o > 0; o >>= 1) {
        if (threadIdx.x < o) red[threadIdx.x] += red[threadIdx.x + o];
        __syncthreads();
    }
    if (threadIdx.x == 0)
        atomicAdd(ws + WS_SCAL + (blockIdx.x < 8 ? 0 : 1), red[0]);
}

// ---- K0c: per-group Gram  G[z1,z2] = (F.F')(R1.R1')(R2.R2') ----
__global__ __launch_bounds__(256) void k0_gram(float* __restrict__ ws) {
    int g = blockIdx.x, t = threadIdx.x;
    __shared__ float Fg[2048], R1g[1024], R2g[1024];
    for (int i = t; i < 2048; i += 256) Fg[i] = ws[WS_FSP + g * 2048 + i];
    for (int i = t; i < 1024; i += 256) {
        R1g[i] = ws[WS_R1SP + g * 1024 + i];
        R2g[i] = ws[WS_R2SP + g * 1024 + i];
    }
    __syncthreads();
    for (int p = t; p < 1024; p += 256) {
        int z1 = p >> 5, z2 = p & 31;
        float dF = 0.f;
        for (int f = 0; f < 64; f++) dF += Fg[z1 * 64 + f] * Fg[z2 * 64 + f];
        float d1 = 0.f, d2 = 0.f;
        for (int r = 0; r < 32; r++) {
            d1 += R1g[z1 * 32 + r] * R1g[z2 * 32 + r];
            d2 += R2g[z1 * 32 + r] * R2g[z2 * 32 + r];
        }
        ws[WS_G + g * 1024 + p] = dF * d1 * d2;
    }
}

// ---- K1: encoder GEMM via bf16 MFMA, split-K partials ----
// block = 64 rows x 64 cols (cols 0-31 = W1/z_mu, 32-63 = W2/z_log)
// wave w: rows rt*64 + w*16 + (lane&15); 4 n-tiles of 16; K chunk = 128/iter
__global__ __launch_bounds__(256) void k1_gemm(const float* __restrict__ feat,
                                               const float* __restrict__ W1,
                                               const float* __restrict__ W2,
                                               float* __restrict__ ws) {
    __shared__ __bf16 Bsm[2][8192];   // fragment-layout W tile, 16 KB per buffer
    const int tid = threadIdx.x;
    const int w = tid >> 6, lane = tid & 63;
    const int fn = lane & 15, q4 = lane >> 4;
    const int rt = blockIdx.x, ks = blockIdx.y;
    const size_t kbase = (size_t)ks * 2048;
    const float* fp = feat + (size_t)(rt * 64 + w * 16 + fn) * NFEAT + kbase + q4 * 8;
    // B staging roles
    const int sn = tid & 31, sarr = (tid >> 5) & 1, skg8 = tid >> 6;
    const float* Wp = (sarr ? W2 : W1) + kbase * 32 + sn;

    float4 rA[2][8];
    float  rB[2][4][8];

    // prologue: chunk 0 loads
    #pragma unroll
    for (int kq = 0; kq < 4; kq++) {
        rA[0][kq * 2]     = *(const float4*)(fp + kq * 32);
        rA[0][kq * 2 + 1] = *(const float4*)(fp + kq * 32 + 4);
    }
    #pragma unroll
    for (int p = 0; p < 4; p++) {
        int kg = p * 4 + skg8;
        #pragma unroll
        for (int j = 0; j < 8; j++) rB[0][p][j] = Wp[(size_t)(kg * 8 + j) * 32];
    }
    #pragma unroll
    for (int p = 0; p < 4; p++) {
        int kg = p * 4 + skg8;
        bf16x8 pk;
        #pragma unroll
        for (int j = 0; j < 8; j++) pk[j] = (__bf16)rB[0][p][j];
        *(bf16x8*)&Bsm[0][(kg * 64 + sarr * 32 + sn) * 8] = pk;
    }
    __syncthreads();

    floatx4 acc0 = {0.f,0.f,0.f,0.f}, acc1 = {0.f,0.f,0.f,0.f};
    floatx4 acc2 = {0.f,0.f,0.f,0.f}, acc3 = {0.f,0.f,0.f,0.f};

    #pragma unroll 2
    for (int cc = 0; cc < 16; cc++) {
        const int cur = cc & 1, nxt = cur ^ 1;
        if (cc < 15) {
            const float* fpn = fp + (cc + 1) * 128;
            #pragma unroll
            for (int kq = 0; kq < 4; kq++) {
                rA[nxt][kq * 2]     = *(const float4*)(fpn + kq * 32);
                rA[nxt][kq * 2 + 1] = *(const float4*)(fpn + kq * 32 + 4);
            }
            const float* wpn = Wp + (size_t)(cc + 1) * 128 * 32;
            #pragma unroll
            for (int p = 0; p < 4; p++) {
                int kg = p * 4 + skg8;
                #pragma unroll
                for (int j = 0; j < 8; j++) rB[nxt][p][j] = wpn[(size_t)(kg * 8 + j) * 32];
            }
        }
        // compute chunk cc
        #pragma unroll
        for (int kq = 0; kq < 4; kq++) {
            float4 lo = rA[cur][kq * 2], hi = rA[cur][kq * 2 + 1];
            bf16x8 af;
            af[0] = (__bf16)lo.x; af[1] = (__bf16)lo.y; af[2] = (__bf16)lo.z; af[3] = (__bf16)lo.w;
            af[4] = (__bf16)hi.x; af[5] = (__bf16)hi.y; af[6] = (__bf16)hi.z; af[7] = (__bf16)hi.w;
            const __bf16* bbase = &Bsm[cur][((kq * 4 + q4) * 64 + fn) * 8];
            bf16x8 b0 = *(const bf16x8*)(bbase);
            bf16x8 b1 = *(const bf16x8*)(bbase + 16 * 8);
            bf16x8 b2 = *(const bf16x8*)(bbase + 32 * 8);
            bf16x8 b3 = *(const bf16x8*)(bbase + 48 * 8);
            acc0 = __builtin_amdgcn_mfma_f32_16x16x32_bf16(af, b0, acc0, 0, 0, 0);
            acc1 = __builtin_amdgcn_mfma_f32_16x16x32_bf16(af, b1, acc1, 0, 0, 0);
            acc2 = __builtin_amdgcn_mfma_f32_16x16x32_bf16(af, b2, acc2, 0, 0, 0);
            acc3 = __builtin_amdgcn_mfma_f32_16x16x32_bf16(af, b3, acc3, 0, 0, 0);
        }
        if (cc < 15) {
            #pragma unroll
            for (int p = 0; p < 4; p++) {
                int kg = p * 4 + skg8;
                bf16x8 pk;
                #pragma unroll
                for (int j = 0; j < 8; j++) pk[j] = (__bf16)rB[nxt][p][j];
                *(bf16x8*)&Bsm[nxt][(kg * 64 + sarr * 32 + sn) * 8] = pk;
            }
        }
        __syncthreads();
    }

    // epilogue: D layout col=lane&15, row=q4*4+reg
    float* zp = ws + WS_ZPART + ((size_t)ks * 1024 + rt * 64 + w * 16) * 64;
    #pragma unroll
    for (int r = 0; r < 4; r++) {
        int brow = q4 * 4 + r;
        zp[(size_t)brow * 64 +  0 + fn] = acc0[r];
        zp[(size_t)brow * 64 + 16 + fn] = acc1[r];
        zp[(size_t)brow * 64 + 32 + fn] = acc2[r];
        zp[(size_t)brow * 64 + 48 + fn] = acc3[r];
    }
}

// ---- K2: T partials + sum(flat^2) partials. block = (batch b, f-slice of 8) ----
__global__ __launch_bounds__(256) void k2_T(const float* __restrict__ feat,
                                            const int* __restrict__ groups,
                                            float* __restrict__ ws) {
    __shared__ float L[8192];      // feat[b, fs*8 .. fs*8+8, :, :]
    __shared__ float sT[8][32];
    __shared__ float sred[256];
    const int b = blockIdx.x >> 3, fs = blockIdx.x & 7;
    const int t = threadIdx.x;
    const int g = groups[b];
    const float* src = feat + (size_t)b * 65536 + fs * 8192;

    float ssl = 0.f;
    #pragma unroll
    for (int it = 0; it < 8; it++) {
        float4 v = *(const float4*)(src + (it * 256 + t) * 4);
        ssl += v.x * v.x + v.y * v.y + v.z * v.z + v.w * v.w;
        *(float4*)&L[(it * 256 + t) * 4] = v;
    }

    const int z = t & 31, fi = t >> 5;
    float4 r2q[8];
    float  r1a[32];
    const float* R2g = ws + WS_R2SP + g * 1024 + z * 32;
    const float* R1g = ws + WS_R1SP + g * 1024 + z * 32;
    #pragma unroll
    for (int q = 0; q < 8; q++) {
        r2q[q] = *(const float4*)(R2g + q * 4);
        float4 rv = *(const float4*)(R1g + q * 4);
        r1a[q * 4] = rv.x; r1a[q * 4 + 1] = rv.y; r1a[q * 4 + 2] = rv.z; r1a[q * 4 + 3] = rv.w;
    }
    __syncthreads();

    const float* Lf = L + fi * 1024;
    float facc = 0.f;
    #pragma unroll
    for (int r = 0; r < 32; r++) {
        float d = 0.f;
        #pragma unroll
        for (int q = 0; q < 8; q++) {
            float4 v = *(const float4*)&Lf[r * 32 + q * 4];
            d += v.x * r2q[q].x + v.y * r2q[q].y + v.z * r2q[q].z + v.w * r2q[q].w;
        }
        facc = fmaf(r1a[r], d, facc);
    }
    float fv = ws[WS_FSP + g * 2048 + z * 64 + fs * 8 + fi];
    sT[fi][z] = fv * facc;
    sred[t] = ssl;
    __syncthreads();
    for (int o = 128; o > 0; o >>= 1) {
        if (t < o) sred[t] += sred[t + o];
        __syncthreads();
    }
    if (t == 0) ws[WS_SSP + fs * 1024 + b] = sred[0];
    if (t < 32) {
        float s = 0.f;
        #pragma unroll
        for (int r = 0; r < 8; r++) s += sT[r][t];
        ws[WS_TP + ((size_t)fs * 1024 + b) * 32 + t] = s;
    }
}

// ---- K3: per-batch epilogue (block=64 threads per batch) ----
__global__ __launch_bounds__(64) void k3_batch(const float* __restrict__ W1,
                                               const float* __restrict__ W2,
                                               const float* __restrict__ b1,
                                               const float* __restrict__ b2,
                                               const float* __restrict__ gemb,
                                               const float* __restrict__ noise,
                                               const float* __restrict__ linW,
                                               const float* __restrict__ linb,
                                               const float* __restrict__ lbias,
                                               const int* __restrict__ groups,
                                               const int* __restrict__ labels,
                                               const float* __restrict__ weights,
                                               float* __restrict__ ws) {
    const int b = blockIdx.x;
    const int t = threadIdx.x;   // 0..63
    const int g = groups[b];
    float sum = 0.f;
    const float* zp = ws + WS_ZPART + (size_t)b * 64 + t;
    #pragma unroll 4
    for (int ks = 0; ks < KS1; ks++) sum += zp[(size_t)ks * 65536];

    __shared__ float s_mu[32], s_sig[32], s_zs0[32], s_zs[32], s_P[32], s_red[96];
    float ge0 = gemb[g * 2], ge1 = gemb[g * 2 + 1];
    if (t < 32) {
        float mu = sum + ge0 * W1[(size_t)65536 * 32 + t] + ge1 * W1[(size_t)65537 * 32 + t] + b1[t];
        s_mu[t] = mu;
    } else {
        int c = t - 32;
        float ls = sum + ge0 * W2[(size_t)65536 * 32 + c] + ge1 * W2[(size_t)65537 * 32 + c] + b2[c];
        s_sig[c] = 1e-6f + expf(ls);
    }
    __syncthreads();
    if (t < 32) s_zs0[t] = s_mu[t] + s_sig[t] * noise[b * 32 + t];
    __syncthreads();
    if (t < 32) {
        float d = linb[t];
        for (int i = 0; i < 32; i++) d = fmaf(s_zs0[i], linW[i * 32 + t], d);
        s_zs[t] = d;
        s_P[t] = softplusf(d);
    }
    __syncthreads();
    if (t < 32) {
        float mu = s_mu[t], sg = s_sig[t];
        float kld = -logf(sg) + 0.5f * (sg * sg + mu * mu - 1.f);
        float Tv = 0.f;
        #pragma unroll
        for (int fs = 0; fs < 8; fs++) Tv += ws[WS_TP + ((size_t)fs * 1024 + b) * 32 + t];
        float pt = s_P[t] * Tv;
        const float* Grow = ws + WS_G + g * 1024 + t * 32;
        float gd = 0.f;
        for (int j = 0; j < 32; j++) gd = fmaf(Grow[j], s_P[j], gd);
        s_red[t] = kld; s_red[32 + t] = pt; s_red[64 + t] = s_P[t] * gd;
    }
    __syncthreads();
    if (t == 0) {
        float kld = 0.f, pt = 0.f, pgp = 0.f;
        for (int i = 0; i < 32; i++) { kld += s_red[i]; pt += s_red[32 + i]; pgp += s_red[64 + i]; }
        float ss = 0.f;
        #pragma unroll
        for (int fs = 0; fs < 8; fs++) ss += ws[WS_SSP + fs * 1024 + b];
        float rec = (ss - 2.f * pt + pgp) * (1.f / 65536.f);
        float l0 = s_zs[0] + lbias[0], l1 = s_zs[1] + lbias[1];
        float l2 = s_zs[2] + lbias[2], l3 = 1.f + lbias[3];
        float m = fmaxf(fmaxf(l0, l1), fmaxf(l2, l3));
        float lse = m + logf(expf(l0 - m) + expf(l1 - m) + expf(l2 - m) + expf(l3 - m));
        int lb = labels[b];
        float ll = ((lb == 0) ? l0 : (lb == 1) ? l1 : (lb == 2) ? l2 : l3) - lse;
        ws[WS_LOSSB + b] = rec - weights[b] * ll + kld;
    }
}

// ---- K4: final scalar ----
__global__ __launch_bounds__(256) void k4_final(const float* __restrict__ ws, float* __restrict__ out) {
    __shared__ float red[256];
    int t = threadIdx.x;
    float s = 0.f;
    for (int i = t; i < 1024; i += 256) s += ws[WS_LOSSB + i];
    red[t] = s;
    __syncthreads();
    for (int o = 128; o > 0; o >>= 1) {
        if (t < o) red[t] += red[t + o];
        __syncthreads();
    }
    if (t == 0) out[0] = red[0] * (1.f / 1024.f) + ws[WS_SCAL] + ws[WS_SCAL + 1];
}

extern "C" void kernel_launch(void* const* d_in, const int* in_sizes, int n_in,
                              void* d_out, int out_size, void* d_ws, size_t ws_size,
                              hipStream_t stream) {
    const float* feat    = (const float*)d_in[0];
    const int*   labels  = (const int*)d_in[1];
    const int*   groups  = (const int*)d_in[2];
    const float* weights = (const float*)d_in[3];
    const float* noise   = (const float*)d_in[4];
    const float* gemb    = (const float*)d_in[5];
    const float* W1      = (const float*)d_in[6];
    const float* b1      = (const float*)d_in[7];
    const float* W2      = (const float*)d_in[8];
    const float* b2      = (const float*)d_in[9];
    const float* ff      = (const float*)d_in[10];
    const float* r1f     = (const float*)d_in[11];
    const float* r2f     = (const float*)d_in[12];
    const float* linW    = (const float*)d_in[13];
    const float* linb    = (const float*)d_in[14];
    const float* lbias   = (const float*)d_in[15];
    float* ws = (float*)d_ws;
    float* out = (float*)d_out;

    hipMemsetAsync(ws + WS_SCAL, 0, 64 * sizeof(float), stream);

    k0_factors<<<256, 256, 0, stream>>>(ff, r1f, r2f, ws);
    k0_varloss<<<12, 256, 0, stream>>>(ws);
    k0_gram<<<16, 256, 0, stream>>>(ws);
    k1_gemm<<<dim3(16, KS1), 256, 0, stream>>>(feat, W1, W2, ws);
    k2_T<<<8192, 256, 0, stream>>>(feat, groups, ws);
    k3_batch<<<1024, 64, 0, stream>>>(W1, W2, b1, b2, gemb, noise, linW, linb, lbias,
                                      groups, labels, weights, ws);
    k4_final<<<1, 256, 0, stream>>>(ws, out);
}

// Round 3
// 483.042 us; speedup vs baseline: 2.0428x; 1.2014x over previous
//
#include <hip/hip_runtime.h>
#include <math.h>

#define NFEAT 65536
#define KS1   32        // k slices (2048 each)
#define NTILE 32        // max 64-row group-uniform tiles

// ---- ws layout (float offsets) ----
#define WS_Z     0          // [1024][64] atomic accum mu|ls   (memset)
#define WS_T     65536      // [1024][32] atomic accum T       (memset)
#define WS_SS    98304      // [1024] sum(flat^2)              (memset)
#define WS_SCAL  99328      // [2] freq_loss, roi_loss         (memset; pad to 99392)
#define WS_FSP   99392      // [16][32][64] softplus freq
#define WS_R1SP  132160     // [16][32][32]
#define WS_R2SP  148544     // [16][32][32]
#define WS_G     164928     // [16][32][32] Gram
#define WS_LOSSB 181312     // [1024]
#define WS_SORTI 182336     // int region: order[2048], tg[32], tb[32], tc[32]

typedef __bf16 bf16x8 __attribute__((ext_vector_type(8)));
typedef float  floatx4 __attribute__((ext_vector_type(4)));

__device__ __forceinline__ float softplusf(float x) {
    return fmaxf(x, 0.f) + log1pf(expf(-fabsf(x)));
}

// ---- sort batches by group into 64-row tiles ----
__global__ __launch_bounds__(256) void k_sort(const int* __restrict__ groups,
                                              float* __restrict__ wsf) {
    int* order = (int*)(wsf + WS_SORTI);
    int* tg = order + 2048; int* tb = order + 2080; int* tc = order + 2112;
    __shared__ int cnt[16], pos[16];
    int t = threadIdx.x;
    if (t < 16) cnt[t] = 0;
    __syncthreads();
    for (int i = t; i < 1024; i += 256) atomicAdd(&cnt[groups[i]], 1);
    __syncthreads();
    if (t == 0) {
        int tt = 0, base = 0;
        for (int g = 0; g < 16; g++) {
            pos[g] = base;
            int c = cnt[g];
            int nt = (c + 63) >> 6;
            for (int j = 0; j < nt; j++) {
                tg[tt] = g; tb[tt] = base + j * 64;
                int rem = c - j * 64;
                tc[tt] = rem < 64 ? rem : 64;
                tt++;
            }
            base += c;
        }
        for (; tt < NTILE; tt++) { tg[tt] = 0; tb[tt] = 0; tc[tt] = 0; }
    }
    __syncthreads();
    for (int i = t; i < 1024; i += 256) {
        int s = atomicAdd(&pos[groups[i]], 1);
        order[s] = i;
    }
    for (int i = 1024 + t; i < 2048; i += 256) order[i] = 0;
}

// ---- K0a: softplus factors ----
__global__ __launch_bounds__(256) void k0_factors(const float* __restrict__ ff,
                                                  const float* __restrict__ r1,
                                                  const float* __restrict__ r2,
                                                  float* __restrict__ ws) {
    int i = blockIdx.x * 256 + threadIdx.x;
    float x;
    if (i < 32768)      x = ff[i];
    else if (i < 49152) x = r1[i - 32768];
    else                x = r2[i - 49152];
    ws[WS_FSP + i] = softplusf(x);
}

// ---- K0b: variance losses ----
__global__ __launch_bounds__(256) void k0_varloss(float* __restrict__ ws) {
    int gid = blockIdx.x * 256 + threadIdx.x;
    float contrib = 0.f;
    if (gid < 2048) {
        const float* F = ws + WS_FSP + gid;
        float sx = 0.f, sx2 = 0.f;
        #pragma unroll
        for (int g = 0; g < 16; g++) { float x = F[g * 2048]; sx += x; sx2 += x * x; }
        contrib = (sx2 - sx * sx * (1.f / 16.f)) * (1.f / 15.f) * (1.f / 64.f);
    } else {
        int p = gid - 2048;
        const float* A = ws + WS_R1SP + p;
        const float* B = ws + WS_R2SP + p;
        float sx = 0.f, sx2 = 0.f, tx = 0.f, tx2 = 0.f;
        #pragma unroll
        for (int g = 0; g < 16; g++) {
            float x = A[g * 1024]; sx += x; sx2 += x * x;
            float y = B[g * 1024]; tx += y; tx2 += y * y;
        }
        contrib = ((sx2 - sx * sx * (1.f / 16.f)) + (tx2 - tx * tx * (1.f / 16.f)))
                  * (1.f / 15.f) * (1.f / 32.f);
    }
    __shared__ float red[256];
    red[threadIdx.x] = contrib;
    __syncthreads();
    for (int o = 128; o > 0; o >>= 1) {
        if (threadIdx.x < o) red[threadIdx.x] += red[threadIdx.x + o];
        __syncthreads();
    }
    if (threadIdx.x == 0)
        atomicAdd(ws + WS_SCAL + (blockIdx.x < 8 ? 0 : 1), red[0]);
}

// ---- K0c: per-group Gram ----
__global__ __launch_bounds__(256) void k0_gram(float* __restrict__ ws) {
    int g = blockIdx.x, t = threadIdx.x;
    __shared__ float Fg[2048], R1g[1024], R2g[1024];
    for (int i = t; i < 2048; i += 256) Fg[i] = ws[WS_FSP + g * 2048 + i];
    for (int i = t; i < 1024; i += 256) {
        R1g[i] = ws[WS_R1SP + g * 1024 + i];
        R2g[i] = ws[WS_R2SP + g * 1024 + i];
    }
    __syncthreads();
    for (int p = t; p < 1024; p += 256) {
        int z1 = p >> 5, z2 = p & 31;
        float dF = 0.f;
        for (int f = 0; f < 64; f++) dF += Fg[z1 * 64 + f] * Fg[z2 * 64 + f];
        float d1 = 0.f, d2 = 0.f;
        for (int r = 0; r < 32; r++) {
            d1 += R1g[z1 * 32 + r] * R1g[z2 * 32 + r];
            d2 += R2g[z1 * 32 + r] * R2g[z2 * 32 + r];
        }
        ws[WS_G + g * 1024 + p] = dF * d1 * d2;
    }
}

// ---- fused: GEMM [64 x 2048] x [2048 x 96] per block; N = W1(32)|W2(32)|Kg(32) ----
__global__ __launch_bounds__(256) void k_fused(const float* __restrict__ feat,
                                               const float* __restrict__ W1,
                                               const float* __restrict__ W2,
                                               float* __restrict__ wsf) {
    const int rt = blockIdx.x, ks = blockIdx.y;
    const int* order = (const int*)(wsf + WS_SORTI);
    const int tcnt = order[2112 + rt];
    if (tcnt == 0) return;
    const int g     = order[2048 + rt];
    const int tbase = order[2080 + rt];

    __shared__ __bf16 Bsm[2][12800];   // 16 kg x stride 100 cols x 8, x2 buffers
    const int tid = threadIdx.x;
    const int w = tid >> 6, lane = tid & 63;
    const int fn = lane & 15, q4 = lane >> 4;
    const size_t kbase = (size_t)ks * 2048;

    const int rowit = w * 16 + fn;
    const int bA = order[tbase + rowit];
    const float* fp = feat + (size_t)bA * NFEAT + kbase + q4 * 8;

    // W staging roles
    const int sn = tid & 31, sarr = (tid >> 5) & 1, skg8 = tid >> 6;
    const float* Wp = (sarr ? W2 : W1) + kbase * 32 + sn;

    // Kg-gen roles
    const int kz = tid & 31, kg8 = tid >> 5;     // kg8 0..7
    const int h = kg8 >> 1;
    float r2v[16];
    {
        const float* R2g = wsf + WS_R2SP + g * 1024 + kz * 32 + (kg8 & 1) * 16;
        float4 a0 = *(const float4*)(R2g);
        float4 a1 = *(const float4*)(R2g + 4);
        float4 a2 = *(const float4*)(R2g + 8);
        float4 a3 = *(const float4*)(R2g + 12);
        r2v[0]=a0.x; r2v[1]=a0.y; r2v[2]=a0.z; r2v[3]=a0.w;
        r2v[4]=a1.x; r2v[5]=a1.y; r2v[6]=a1.z; r2v[7]=a1.w;
        r2v[8]=a2.x; r2v[9]=a2.y; r2v[10]=a2.z; r2v[11]=a2.w;
        r2v[12]=a3.x; r2v[13]=a3.y; r2v[14]=a3.z; r2v[15]=a3.w;
    }
    const float* Fzp  = wsf + WS_FSP  + g * 2048 + kz * 64 + ks * 2;  // + (cc>>3)
    const float* R1zp = wsf + WS_R1SP + g * 1024 + kz * 32;           // + (cc&7)*4+h

    float4 rA[2][8];
    float  rB[4][8];

    // ---- prologue: stage chunk 0 ----
    #pragma unroll
    for (int kq = 0; kq < 4; kq++) {
        rA[0][kq * 2]     = *(const float4*)(fp + kq * 32);
        rA[0][kq * 2 + 1] = *(const float4*)(fp + kq * 32 + 4);
    }
    #pragma unroll
    for (int p = 0; p < 4; p++) {
        int kg = p * 4 + skg8;
        #pragma unroll
        for (int j = 0; j < 8; j++) rB[p][j] = Wp[(size_t)(kg * 8 + j) * 32];
    }
    {
        float Fv = Fzp[0], R1v = R1zp[h];
        #pragma unroll
        for (int p = 0; p < 4; p++) {
            int kg = p * 4 + skg8;
            bf16x8 pk;
            #pragma unroll
            for (int j = 0; j < 8; j++) pk[j] = (__bf16)rB[p][j];
            *(bf16x8*)&Bsm[0][(kg * 100 + sarr * 32 + sn) * 8] = pk;
        }
        float cf = Fv * R1v;
        #pragma unroll
        for (int ih = 0; ih < 2; ih++) {
            bf16x8 pk;
            #pragma unroll
            for (int j = 0; j < 8; j++) pk[j] = (__bf16)(cf * r2v[ih * 8 + j]);
            *(bf16x8*)&Bsm[0][((kg8 * 2 + ih) * 100 + 64 + kz) * 8] = pk;
        }
    }
    __syncthreads();

    floatx4 acc0 = {0,0,0,0}, acc1 = {0,0,0,0}, acc2 = {0,0,0,0};
    floatx4 acc3 = {0,0,0,0}, acc4 = {0,0,0,0}, acc5 = {0,0,0,0};
    float ssl = 0.f;

    #pragma unroll 2
    for (int cc = 0; cc < 16; cc++) {
        const int cur = cc & 1, nxt = cur ^ 1;
        float FvN = 0.f, R1vN = 0.f;
        if (cc < 15) {
            const float* fpn = fp + (cc + 1) * 128;
            #pragma unroll
            for (int kq = 0; kq < 4; kq++) {
                rA[nxt][kq * 2]     = *(const float4*)(fpn + kq * 32);
                rA[nxt][kq * 2 + 1] = *(const float4*)(fpn + kq * 32 + 4);
            }
            const float* wpn = Wp + (size_t)(cc + 1) * 128 * 32;
            #pragma unroll
            for (int p = 0; p < 4; p++) {
                int kg = p * 4 + skg8;
                #pragma unroll
                for (int j = 0; j < 8; j++) rB[p][j] = wpn[(size_t)(kg * 8 + j) * 32];
            }
            FvN  = Fzp[(cc + 1) >> 3];
            R1vN = R1zp[((cc + 1) & 7) * 4 + h];
        }
        // compute chunk cc
        #pragma unroll
        for (int kq = 0; kq < 4; kq++) {
            float4 lo = rA[cur][kq * 2], hi = rA[cur][kq * 2 + 1];
            ssl += lo.x*lo.x + lo.y*lo.y + lo.z*lo.z + lo.w*lo.w
                 + hi.x*hi.x + hi.y*hi.y + hi.z*hi.z + hi.w*hi.w;
            bf16x8 af;
            af[0]=(__bf16)lo.x; af[1]=(__bf16)lo.y; af[2]=(__bf16)lo.z; af[3]=(__bf16)lo.w;
            af[4]=(__bf16)hi.x; af[5]=(__bf16)hi.y; af[6]=(__bf16)hi.z; af[7]=(__bf16)hi.w;
            const __bf16* bb = &Bsm[cur][((kq * 4 + q4) * 100 + fn) * 8];
            bf16x8 b0 = *(const bf16x8*)(bb);
            bf16x8 b1 = *(const bf16x8*)(bb + 16 * 8);
            bf16x8 b2 = *(const bf16x8*)(bb + 32 * 8);
            bf16x8 b3 = *(const bf16x8*)(bb + 48 * 8);
            bf16x8 b4 = *(const bf16x8*)(bb + 64 * 8);
            bf16x8 b5 = *(const bf16x8*)(bb + 80 * 8);
            acc0 = __builtin_amdgcn_mfma_f32_16x16x32_bf16(af, b0, acc0, 0, 0, 0);
            acc1 = __builtin_amdgcn_mfma_f32_16x16x32_bf16(af, b1, acc1, 0, 0, 0);
            acc2 = __builtin_amdgcn_mfma_f32_16x16x32_bf16(af, b2, acc2, 0, 0, 0);
            acc3 = __builtin_amdgcn_mfma_f32_16x16x32_bf16(af, b3, acc3, 0, 0, 0);
            acc4 = __builtin_amdgcn_mfma_f32_16x16x32_bf16(af, b4, acc4, 0, 0, 0);
            acc5 = __builtin_amdgcn_mfma_f32_16x16x32_bf16(af, b5, acc5, 0, 0, 0);
        }
        if (cc < 15) {
            #pragma unroll
            for (int p = 0; p < 4; p++) {
                int kg = p * 4 + skg8;
                bf16x8 pk;
                #pragma unroll
                for (int j = 0; j < 8; j++) pk[j] = (__bf16)rB[p][j];
                *(bf16x8*)&Bsm[nxt][(kg * 100 + sarr * 32 + sn) * 8] = pk;
            }
            float cf = FvN * R1vN;
            #pragma unroll
            for (int ih = 0; ih < 2; ih++) {
                bf16x8 pk;
                #pragma unroll
                for (int j = 0; j < 8; j++) pk[j] = (__bf16)(cf * r2v[ih * 8 + j]);
                *(bf16x8*)&Bsm[nxt][((kg8 * 2 + ih) * 100 + 64 + kz) * 8] = pk;
            }
            __syncthreads();
        }
    }

    // ---- epilogue ----
    float ssv = ssl + __shfl_xor(ssl, 16, 64);
    ssv += __shfl_xor(ssv, 32, 64);
    if (q4 == 0 && rowit < tcnt) atomicAdd(wsf + WS_SS + bA, ssv);

    #pragma unroll
    for (int r = 0; r < 4; r++) {
        int rit = w * 16 + q4 * 4 + r;
        if (rit < tcnt) {
            int b = order[tbase + rit];
            atomicAdd(wsf + WS_Z + b * 64 +  0 + fn, acc0[r]);
            atomicAdd(wsf + WS_Z + b * 64 + 16 + fn, acc1[r]);
            atomicAdd(wsf + WS_Z + b * 64 + 32 + fn, acc2[r]);
            atomicAdd(wsf + WS_Z + b * 64 + 48 + fn, acc3[r]);
            atomicAdd(wsf + WS_T + b * 32 +  0 + fn, acc4[r]);
            atomicAdd(wsf + WS_T + b * 32 + 16 + fn, acc5[r]);
        }
    }
}

// ---- K3: per-batch epilogue ----
__global__ __launch_bounds__(64) void k3_batch(const float* __restrict__ W1,
                                               const float* __restrict__ W2,
                                               const float* __restrict__ b1,
                                               const float* __restrict__ b2,
                                               const float* __restrict__ gemb,
                                               const float* __restrict__ noise,
                                               const float* __restrict__ linW,
                                               const float* __restrict__ linb,
                                               const float* __restrict__ lbias,
                                               const int* __restrict__ groups,
                                               const int* __restrict__ labels,
                                               const float* __restrict__ weights,
                                               float* __restrict__ ws) {
    const int b = blockIdx.x;
    const int t = threadIdx.x;
    const int g = groups[b];
    float sum = ws[WS_Z + b * 64 + t];

    __shared__ float s_mu[32], s_sig[32], s_zs0[32], s_zs[32], s_P[32], s_red[96];
    float ge0 = gemb[g * 2], ge1 = gemb[g * 2 + 1];
    if (t < 32) {
        s_mu[t] = sum + ge0 * W1[(size_t)65536 * 32 + t] + ge1 * W1[(size_t)65537 * 32 + t] + b1[t];
    } else {
        int c = t - 32;
        float ls = sum + ge0 * W2[(size_t)65536 * 32 + c] + ge1 * W2[(size_t)65537 * 32 + c] + b2[c];
        s_sig[c] = 1e-6f + expf(ls);
    }
    __syncthreads();
    if (t < 32) s_zs0[t] = s_mu[t] + s_sig[t] * noise[b * 32 + t];
    __syncthreads();
    if (t < 32) {
        float d = linb[t];
        for (int i = 0; i < 32; i++) d = fmaf(s_zs0[i], linW[i * 32 + t], d);
        s_zs[t] = d;
        s_P[t] = softplusf(d);
    }
    __syncthreads();
    if (t < 32) {
        float mu = s_mu[t], sg = s_sig[t];
        float kld = -logf(sg) + 0.5f * (sg * sg + mu * mu - 1.f);
        float pt = s_P[t] * ws[WS_T + b * 32 + t];
        const float* Grow = ws + WS_G + g * 1024 + t * 32;
        float gd = 0.f;
        for (int j = 0; j < 32; j++) gd = fmaf(Grow[j], s_P[j], gd);
        s_red[t] = kld; s_red[32 + t] = pt; s_red[64 + t] = s_P[t] * gd;
    }
    __syncthreads();
    if (t == 0) {
        float kld = 0.f, pt = 0.f, pgp = 0.f;
        for (int i = 0; i < 32; i++) { kld += s_red[i]; pt += s_red[32 + i]; pgp += s_red[64 + i]; }
        float rec = (ws[WS_SS + b] - 2.f * pt + pgp) * (1.f / 65536.f);
        float l0 = s_zs[0] + lbias[0], l1 = s_zs[1] + lbias[1];
        float l2 = s_zs[2] + lbias[2], l3 = 1.f + lbias[3];
        float m = fmaxf(fmaxf(l0, l1), fmaxf(l2, l3));
        float lse = m + logf(expf(l0 - m) + expf(l1 - m) + expf(l2 - m) + expf(l3 - m));
        int lb = labels[b];
        float ll = ((lb == 0) ? l0 : (lb == 1) ? l1 : (lb == 2) ? l2 : l3) - lse;
        ws[WS_LOSSB + b] = rec - weights[b] * ll + kld;
    }
}

// ---- K4: final scalar ----
__global__ __launch_bounds__(256) void k4_final(const float* __restrict__ ws, float* __restrict__ out) {
    __shared__ float red[256];
    int t = threadIdx.x;
    float s = 0.f;
    for (int i = t; i < 1024; i += 256) s += ws[WS_LOSSB + i];
    red[t] = s;
    __syncthreads();
    for (int o = 128; o > 0; o >>= 1) {
        if (t < o) red[t] += red[t + o];
        __syncthreads();
    }
    if (t == 0) out[0] = red[0] * (1.f / 1024.f) + ws[WS_SCAL] + ws[WS_SCAL + 1];
}

extern "C" void kernel_launch(void* const* d_in, const int* in_sizes, int n_in,
                              void* d_out, int out_size, void* d_ws, size_t ws_size,
                              hipStream_t stream) {
    const float* feat    = (const float*)d_in[0];
    const int*   labels  = (const int*)d_in[1];
    const int*   groups  = (const int*)d_in[2];
    const float* weights = (const float*)d_in[3];
    const float* noise   = (const float*)d_in[4];
    const float* gemb    = (const float*)d_in[5];
    const float* W1      = (const float*)d_in[6];
    const float* b1      = (const float*)d_in[7];
    const float* W2      = (const float*)d_in[8];
    const float* b2      = (const float*)d_in[9];
    const float* ff      = (const float*)d_in[10];
    const float* r1f     = (const float*)d_in[11];
    const float* r2f     = (const float*)d_in[12];
    const float* linW    = (const float*)d_in[13];
    const float* linb    = (const float*)d_in[14];
    const float* lbias   = (const float*)d_in[15];
    float* ws = (float*)d_ws;
    float* out = (float*)d_out;

    // zero Z/T/SS/SCAL accumulators
    hipMemsetAsync(ws, 0, 99392 * sizeof(float), stream);

    k_sort<<<1, 256, 0, stream>>>(groups, ws);
    k0_factors<<<256, 256, 0, stream>>>(ff, r1f, r2f, ws);
    k0_varloss<<<12, 256, 0, stream>>>(ws);
    k0_gram<<<16, 256, 0, stream>>>(ws);
    k_fused<<<dim3(NTILE, KS1), 256, 0, stream>>>(feat, W1, W2, ws);
    k3_batch<<<1024, 64, 0, stream>>>(W1, W2, b1, b2, gemb, noise, linW, linb, lbias,
                                      groups, labels, weights, ws);
    k4_final<<<1, 256, 0, stream>>>(ws, out);
}